// Round 13
// baseline (177.545 us; speedup 1.0000x reference)
//
#include <hip/hip_runtime.h>

// STKBranch double-softmax attention, R13: 32x32x16 MFMA + key-interleaved P pack.
//   pass0: one kernel converts K->f16 [h][key][d] and V->f16 transposed+interleaved
//          [h][d][ik], ik = 2*(key%32)+(key/32) within each 64-key tile.
//   main:  4 waves x 32 q-rows; 32x32x16 MFMAs halve LDS b128 reads per FLOP;
//          P packs as b32 pairs (kg0,kg1) thanks to interleave; Ps wave-private;
//          K/V staged via global_load_lds (source-XOR swizzle); 1 barrier/tile.
// Math: L = scale*q@k^T ; w = softmax(2L) ; attn = softmax(L*w) ; out = attn@v
// |L| <= ~7 -> no max-subtraction. B=4 H=8 N=2048 D=64 fp32 io.

typedef _Float16 f16;
typedef f16 f16x8 __attribute__((ext_vector_type(8)));
typedef float f32x16 __attribute__((ext_vector_type(16)));

#define MFMA32(a, b, c) __builtin_amdgcn_mfma_f32_32x32x16_f16((a), (b), (c), 0, 0, 0)
#define EXP2(x) __builtin_amdgcn_exp2f(x)   // v_exp_f32: D = 2^S0

#define N_CTX 2048
#define DH 64
#define KT 64
#define NKT (N_CTX / KT)
#define ROWS 128          // 4 waves x 32 q-rows
#define QS 72             // Qs/Ps row stride (f16)
#define HEAD_ELEMS (N_CTX * DH)
#define C2 2.885390081777927f     // 2*log2(e), folded into staged Q

__device__ inline unsigned pk(float a, float b) {
    typedef __fp16 fp16x2_t __attribute__((ext_vector_type(2)));
    union { fp16x2_t v; unsigned u; } x;
    x.v = __builtin_amdgcn_cvt_pkrtz(a, b);
    return x.u;
}

__device__ inline void load16_lds(const f16* g, f16* l) {
    __builtin_amdgcn_global_load_lds(
        (const __attribute__((address_space(1))) void*)g,
        (__attribute__((address_space(3))) void*)l, 16, 0, 0);
}

// ---- pass0: K f32->f16 same layout; V f32 -> f16 [h][d][ik] interleaved ----
__global__ __launch_bounds__(256)
void cvt_kv(const float* __restrict__ k, const float* __restrict__ v,
            f16* __restrict__ ko, f16* __restrict__ vto) {
    __shared__ float Vs[64][65];
    const int bh = blockIdx.x & 31;
    const int kt = blockIdx.x >> 5;
    const int t  = threadIdx.x;
    const float* kb = k + (size_t)bh * HEAD_ELEMS + (size_t)kt * KT * DH;
    f16* kob = ko + (size_t)bh * HEAD_ELEMS + (size_t)kt * KT * DH;
    #pragma unroll
    for (int it = 0; it < 2; ++it) {
        int i = (it * 256 + t) * 8;
        float4 a = *(const float4*)&kb[i];
        float4 b = *(const float4*)&kb[i + 4];
        *(uint4*)&kob[i] = make_uint4(pk(a.x, a.y), pk(a.z, a.w), pk(b.x, b.y), pk(b.z, b.w));
    }
    const float* vb = v + (size_t)bh * HEAD_ELEMS + (size_t)kt * KT * DH;
    #pragma unroll
    for (int it = 0; it < 4; ++it) {
        int idx = it * 256 + t;
        int row = idx >> 4, c4 = idx & 15;
        *(float4*)&Vs[row][c4 * 4] = *(const float4*)&vb[row * DH + c4 * 4];
    }
    __syncthreads();
    // thread t: d = t>>2, writes ik = sub*16 .. +15  (ik=2c -> key c, ik=2c+1 -> key c+32)
    int d = t >> 2, sub = t & 3;
    unsigned w[8];
    #pragma unroll
    for (int j = 0; j < 8; ++j) {
        int c = sub * 8 + j;
        w[j] = pk(Vs[c][d], Vs[c + 32][d]);
    }
    f16* ob = vto + (size_t)bh * HEAD_ELEMS + (size_t)d * N_CTX + kt * KT + sub * 16;
    *(uint4*)(ob)     = make_uint4(w[0], w[1], w[2], w[3]);
    *(uint4*)(ob + 8) = make_uint4(w[4], w[5], w[6], w[7]);
}

// ---- main ----
__global__ __launch_bounds__(256, 2)
void stk_attn_mfma(const float* __restrict__ qg, const f16* __restrict__ kh,
                   const f16* __restrict__ vth, const float* __restrict__ sg,
                   float* __restrict__ og) {
    __shared__ f16 Qs[ROWS * QS];       // 18432 B
    __shared__ f16 Ks[2][KT * DH];      // 16384 B chunk-swizzled: p = key*8 + (dc^(key&7))
    __shared__ f16 Vt[2][DH * KT];      // 16384 B chunk-swizzled: p = d*8 + (ikc^(d&7))
    __shared__ f16 Ps[4][32 * QS];      // 18432 B wave-private [row][ik], stride 72
                                        // total 69632 B -> 2 blocks/CU

    const int tid  = threadIdx.x;
    const int wv   = tid >> 6;        // 0..3
    const int lane = tid & 63;
    const int l31  = lane & 31;
    const int lh   = lane >> 5;       // 0/1
    const int bh   = blockIdx.x & 31; // XCD swizzle
    const int q0   = (blockIdx.x >> 5) * ROWS;
    const float scale2 = sg[0] * C2;  // acc = 2L*log2e

    const float* qb = qg + (size_t)bh * HEAD_ELEMS;
    const f16*   kb = kh + (size_t)bh * HEAD_ELEMS;
    const f16*   vtb = vth + (size_t)bh * HEAD_ELEMS;
    float*       ob = og + (size_t)bh * HEAD_ELEMS;

    // ---- stage Q (scale2 folded) ----
    #pragma unroll
    for (int it = 0; it < 8; ++it) {
        int idx = it * 256 + tid;
        int row = idx >> 4, c4 = idx & 15;
        float4 v = *(const float4*)&qb[((size_t)(q0 + row)) * DH + c4 * 4];
        *(uint2*)&Qs[row * QS + c4 * 4] =
            make_uint2(pk(v.x * scale2, v.y * scale2), pk(v.z * scale2, v.w * scale2));
    }
    __syncthreads();

    // ---- Q A-frags: A[m=l31][k = km*16 + lh*8 + j] ----
    f16x8 aq[4];
    #pragma unroll
    for (int km = 0; km < 4; ++km)
        aq[km] = *(const f16x8*)&Qs[(wv * 32 + l31) * QS + km * 16 + lh * 8];

    // ---- staging src offsets (XOR chunk swizzle) & LDS read offsets ----
    const int c0   = (wv * 2) * 64 + lane;
    const int c1   = c0 + 64;
    const int key0 = c0 >> 3, key1 = c1 >> 3;
    const int ks_src0 = key0 * DH + (((c0 & 7) ^ (key0 & 7)) * 8);
    const int ks_src1 = key1 * DH + (((c1 & 7) ^ (key1 & 7)) * 8);
    const long vt_src0 = (long)key0 * N_CTX + (((c0 & 7) ^ (key0 & 7)) * 8);
    const long vt_src1 = (long)key1 * N_CTX + (((c1 & 7) ^ (key1 & 7)) * 8);
    const int dst0 = (wv * 2) * 512, dst1 = dst0 + 512;
    const int x8 = l31 & 7;
    int xo[4];
    #pragma unroll
    for (int km = 0; km < 4; ++km) xo[km] = ((2 * km + lh) ^ x8) * 8;
    const int gb0 = l31 * 64, gb1 = (32 + l31) * 64;   // key/d group bases
    f16* const ps_wv = &Ps[wv][0];

    // =============== PASS 1: s1 = sum exp(2L) ===============
    float s1[16] = {0};
    load16_lds(kb + ks_src0, &Ks[0][dst0]);
    load16_lds(kb + ks_src1, &Ks[0][dst1]);
    __syncthreads();
    for (int kt = 0; kt < NKT; ++kt) {
        const int cur = kt & 1;
        if (kt + 1 < NKT) {
            const f16* src = kb + (kt + 1) * (KT * DH);
            load16_lds(src + ks_src0, &Ks[cur ^ 1][dst0]);
            load16_lds(src + ks_src1, &Ks[cur ^ 1][dst1]);
        }
        #pragma unroll
        for (int kg = 0; kg < 2; ++kg) {
            const int gb = kg ? gb1 : gb0;
            f32x16 acc;
            #pragma unroll
            for (int i = 0; i < 16; ++i) acc[i] = 0.f;
            #pragma unroll
            for (int km = 0; km < 4; ++km) {
                f16x8 b = *(const f16x8*)&Ks[cur][gb + xo[km]];
                acc = MFMA32(aq[km], b, acc);
            }
            #pragma unroll
            for (int r = 0; r < 16; ++r)
                s1[r] += EXP2(acc[r]);
        }
        __syncthreads();
    }
    float inv1[16];
    #pragma unroll
    for (int r = 0; r < 16; ++r) {
        float v = s1[r];
        v += __shfl_xor(v, 1, 64);
        v += __shfl_xor(v, 2, 64);
        v += __shfl_xor(v, 4, 64);
        v += __shfl_xor(v, 8, 64);
        v += __shfl_xor(v, 16, 64);   // 32 cols per row live in one 32-lane half
        inv1[r] = 0.5f / v;           // e2 = exp2((acc*e1) * 0.5/s1)
    }

    // =============== PASS 2: e2, O += e2*V ===============
    float l2[16] = {0};
    f32x16 O0, O1;
    #pragma unroll
    for (int i = 0; i < 16; ++i) { O0[i] = 0.f; O1[i] = 0.f; }

    load16_lds(kb + ks_src0, &Ks[0][dst0]);
    load16_lds(kb + ks_src1, &Ks[0][dst1]);
    load16_lds(vtb + vt_src0, &Vt[0][dst0]);
    load16_lds(vtb + vt_src1, &Vt[0][dst1]);
    __syncthreads();
    for (int kt = 0; kt < NKT; ++kt) {
        const int cur = kt & 1;
        if (kt + 1 < NKT) {
            const f16* src = kb + (kt + 1) * (KT * DH);
            load16_lds(src + ks_src0, &Ks[cur ^ 1][dst0]);
            load16_lds(src + ks_src1, &Ks[cur ^ 1][dst1]);
            load16_lds(vtb + vt_src0 + (kt + 1) * KT, &Vt[cur ^ 1][dst0]);
            load16_lds(vtb + vt_src1 + (kt + 1) * KT, &Vt[cur ^ 1][dst1]);
        }
        // QK^T: two 32-key groups
        f32x16 a0, a1;
        #pragma unroll
        for (int i = 0; i < 16; ++i) { a0[i] = 0.f; a1[i] = 0.f; }
        #pragma unroll
        for (int km = 0; km < 4; ++km) {
            f16x8 b0 = *(const f16x8*)&Ks[cur][gb0 + xo[km]];
            f16x8 b1 = *(const f16x8*)&Ks[cur][gb1 + xo[km]];
            a0 = MFMA32(aq[km], b0, a0);
            a1 = MFMA32(aq[km], b1, a1);
        }
        // softmax chain + packed b32 Ps write (ik = 2*col + kg)
        #pragma unroll
        for (int r = 0; r < 16; ++r) {
            int row_r = (r & 3) + 8 * (r >> 2) + 4 * lh;
            float e10 = EXP2(a0[r]);
            float e20 = EXP2((a0[r] * e10) * inv1[r]);
            float e11 = EXP2(a1[r]);
            float e21 = EXP2((a1[r] * e11) * inv1[r]);
            l2[r] += e20 + e21;
            *(unsigned*)&ps_wv[row_r * QS + 2 * l31] = pk(e20, e21);
        }
        // PV: A = P[m=l31][ik], B = Vt[ik][d]
        #pragma unroll
        for (int km = 0; km < 4; ++km) {
            f16x8 ap = *(const f16x8*)&ps_wv[l31 * QS + km * 16 + lh * 8];
            f16x8 bv0 = *(const f16x8*)&Vt[cur][gb0 + xo[km]];
            f16x8 bv1 = *(const f16x8*)&Vt[cur][gb1 + xo[km]];
            O0 = MFMA32(ap, bv0, O0);
            O1 = MFMA32(ap, bv1, O1);
        }
        __syncthreads();   // protects Ks/Vt swap; drains global_load_lds
    }

    // ---- finalize ----
    float invl2[16];
    #pragma unroll
    for (int r = 0; r < 16; ++r) {
        float v = l2[r];
        v += __shfl_xor(v, 1, 64);
        v += __shfl_xor(v, 2, 64);
        v += __shfl_xor(v, 4, 64);
        v += __shfl_xor(v, 8, 64);
        v += __shfl_xor(v, 16, 64);
        invl2[r] = 1.0f / v;
    }
    #pragma unroll
    for (int r = 0; r < 16; ++r) {
        int row = q0 + wv * 32 + (r & 3) + 8 * (r >> 2) + 4 * lh;
        ob[(size_t)row * DH + l31]      = O0[r] * invl2[r];
        ob[(size_t)row * DH + 32 + l31] = O1[r] * invl2[r];
    }
}

extern "C" void kernel_launch(void* const* d_in, const int* in_sizes, int n_in,
                              void* d_out, int out_size, void* d_ws, size_t ws_size,
                              hipStream_t stream) {
    const float* q = (const float*)d_in[0];
    const float* k = (const float*)d_in[1];
    const float* v = (const float*)d_in[2];
    const float* s = (const float*)d_in[3];
    float* out = (float*)d_out;
    f16* kf  = (f16*)d_ws;                             // 8,388,608 B
    f16* vtf = (f16*)((char*)d_ws + 8388608);          // 8,388,608 B
    cvt_kv<<<1024, 256, 0, stream>>>(k, v, kf, vtf);
    dim3 grid(32 * 16);   // bh = blockIdx&31 (XCD swizzle), q-tile = blockIdx>>5
    stk_attn_mfma<<<grid, 256, 0, stream>>>(q, kf, vtf, s, out);
}